// Round 1
// baseline (154.632 us; speedup 1.0000x reference)
//
#include <hip/hip_runtime.h>

#define LAM 0.5f
#define MU 0.1f
#define RHO 0.05f
#define CLS 10

__device__ __forceinline__ float waveReduceSum(float v) {
#pragma unroll
    for (int off = 32; off; off >>= 1) v += __shfl_down(v, off, 64);
    return v;
}

// Kernel 1: log-softmax of predictions -> logp[B*C], plus wstar accumulator
__global__ __launch_bounds__(256) void logp_kernel(
    const float* __restrict__ pred, const int* __restrict__ tgt,
    float* __restrict__ logp, float* __restrict__ wstar_acc, int B) {
    int b = blockIdx.x * 256 + threadIdx.x;
    float local = 0.f;
    if (b < B) {
        float x[CLS];
        const float2* p2 = reinterpret_cast<const float2*>(pred + (size_t)b * CLS);
#pragma unroll
        for (int j = 0; j < CLS / 2; j++) { float2 v = p2[j]; x[2 * j] = v.x; x[2 * j + 1] = v.y; }
        float m = x[0];
#pragma unroll
        for (int c = 1; c < CLS; c++) m = fmaxf(m, x[c]);
        float z = 0.f;
#pragma unroll
        for (int c = 0; c < CLS; c++) z += __expf(x[c] - m);
        float lse = m + __logf(z);
        float2* o2 = reinterpret_cast<float2*>(logp + (size_t)b * CLS);
#pragma unroll
        for (int j = 0; j < CLS / 2; j++)
            o2[j] = make_float2(x[2 * j] - lse, x[2 * j + 1] - lse);
        int t = tgt[b];
        // avoid runtime-indexed register array (would spill to scratch)
#pragma unroll
        for (int c = 0; c < CLS; c++) local += (c == t) ? (lse - x[c]) : 0.f;
    }
    float sum = waveReduceSum(local);
    if ((threadIdx.x & 63) == 0) atomicAdd(wstar_acc, sum);
}

// Kernel 2: streaming pass over noise. Each block handles one s.
// accW[s]  += sum_b sum_c softmax(noise+oh)*logp      (will be negated later)
// accWt[s] += sum_b sum_c softmax(LAM*noise+oh)*logp
// accN2[s] += sum_b sum_c noise^2
__global__ __launch_bounds__(256) void main_kernel(
    const float* __restrict__ noise, const float* __restrict__ logp,
    const int* __restrict__ tgt,
    float* __restrict__ accW, float* __restrict__ accWt, float* __restrict__ accN2,
    int B, int blocksPerS, int iters) {
    int s = blockIdx.x / blocksPerS;
    int blk = blockIdx.x % blocksPerS;
    const float* nrow = noise + (size_t)s * B * CLS;

    float wn = 0.f, wtn = 0.f, n2 = 0.f;
    int base = blk * 256 * iters + threadIdx.x;
    for (int k = 0; k < iters; k++) {
        int b = base + k * 256;
        if (b >= B) break;
        float n[CLS], lp[CLS];
        const float2* r2 = reinterpret_cast<const float2*>(nrow + (size_t)b * CLS);
        const float2* l2 = reinterpret_cast<const float2*>(logp + (size_t)b * CLS);
#pragma unroll
        for (int j = 0; j < CLS / 2; j++) { float2 v = r2[j]; n[2 * j] = v.x; n[2 * j + 1] = v.y; }
#pragma unroll
        for (int j = 0; j < CLS / 2; j++) { float2 v = l2[j]; lp[2 * j] = v.x; lp[2 * j + 1] = v.y; }
        int t = tgt[b];
        float Z = 0.f, dot = 0.f, Zl = 0.f, dotl = 0.f, sq = 0.f;
#pragma unroll
        for (int c = 0; c < CLS; c++) {
            float oh = (c == t) ? 1.f : 0.f;
            float e  = __expf(n[c] + oh);
            float el = __expf(LAM * n[c] + oh);
            Z  += e;
            Zl += el;
            dot  = fmaf(e,  lp[c], dot);
            dotl = fmaf(el, lp[c], dotl);
            sq   = fmaf(n[c], n[c], sq);
        }
        wn  += dot / Z;
        wtn += dotl / Zl;
        n2  += sq;
    }
    float rw  = waveReduceSum(wn);
    float rwt = waveReduceSum(wtn);
    float rn2 = waveReduceSum(n2);
    if ((threadIdx.x & 63) == 0) {
        atomicAdd(&accW[s],  rw);
        atomicAdd(&accWt[s], rwt);
        atomicAdd(&accN2[s], rn2);
    }
}

// Kernel 3: epilogue — compute sc terms and final scalar.
__global__ __launch_bounds__(256) void final_kernel(
    const float* __restrict__ ws, float* __restrict__ out, int B, int S) {
    // ws layout: [0,S)=accW, [S,2S)=accWt, [2S,3S)=accN2, [3S]=wstar_acc
    __shared__ float smem[4];
    int s = threadIdx.x;
    float invB = 1.0f / (float)B;
    float wstar = ws[3 * S] * invB;
    float local = 0.f;
    if (s < S) {
        float w  = -ws[s] * invB;
        float wt = -ws[S + s] * invB;
        float n2 = ws[2 * S + s];
        float sc1 = fmaxf(wstar - wt, 0.f);
        float sc2 = fmaxf(wstar - w + MU * n2 * 0.5f, 0.f);
        float sc3 = fmaxf(wt - (1.f - LAM) * wstar + LAM * w
                          + MU * LAM * (1.f - LAM) * n2 * 0.5f, 0.f);
        local = sc1 + sc2 + sc3;
    }
    float sum = waveReduceSum(local);
    int lane = threadIdx.x & 63, wid = threadIdx.x >> 6;
    if (lane == 0) smem[wid] = sum;
    __syncthreads();
    if (threadIdx.x == 0) {
        float sc = smem[0] + smem[1] + smem[2] + smem[3];
        out[0] = wstar + RHO * sc;
    }
}

extern "C" void kernel_launch(void* const* d_in, const int* in_sizes, int n_in,
                              void* d_out, int out_size, void* d_ws, size_t ws_size,
                              hipStream_t stream) {
    const float* pred  = (const float*)d_in[0];
    const int*   tgt   = (const int*)d_in[1];
    const float* noise = (const float*)d_in[2];
    float* out = (float*)d_out;

    int B = in_sizes[1];
    int S = in_sizes[2] / in_sizes[0];

    float* ws = (float*)d_ws;
    // accumulators: 3*S + 1 floats at ws[0]; logp at ws+512 (8/16B aligned)
    float* accW  = ws;
    float* accWt = ws + S;
    float* accN2 = ws + 2 * S;
    float* wstarAcc = ws + 3 * S;
    float* logp = ws + 512;

    hipMemsetAsync(d_ws, 0, 2048, stream);

    logp_kernel<<<(B + 255) / 256, 256, 0, stream>>>(pred, tgt, logp, wstarAcc, B);

    const int blocksPerS = 32;
    int iters = (B + blocksPerS * 256 - 1) / (blocksPerS * 256);
    main_kernel<<<S * blocksPerS, 256, 0, stream>>>(noise, logp, tgt,
                                                    accW, accWt, accN2,
                                                    B, blocksPerS, iters);

    final_kernel<<<1, 256, 0, stream>>>(ws, out, B, S);
}